// Round 8
// baseline (917.655 us; speedup 1.0000x reference)
//
#include <hip/hip_runtime.h>
#include <cstdint>
#include <cstddef>

// RWKV_Tmix_headmixer — round 8: XCD load-balance fix + ablation probes.
// sc=(x+tbi)&7 balances the triangular chunk work across XCDs.
// attn_apply<MODE>: 0=full, 1=no-e/no-barriers (wave-independent),
// 5=const-e with barriers. Probes run on a 2x grid into P (garbage),
// real <0> runs last and overwrites -> output exact.
// B=1, T=2048, C=1024, H=16, K=64.

#define C_DIM 1024
#define HEADS 16
#define TQ 16            // t rows per attention block
#define SCH 256          // s-chunk per block
#define PADS 40          // ybuf inner stride (bf16)
#define EPS 36           // ep f32 stride (16B-aligned rows)

typedef unsigned short ushort_t;
typedef __attribute__((ext_vector_type(8))) short bf16x8;
typedef __attribute__((ext_vector_type(4))) float f32x4;

#define MFMA16(a, b, c) __builtin_amdgcn_mfma_f32_16x16x32_bf16(a, b, c, 0, 0, 0)

__device__ __forceinline__ unsigned int f2bf_u(float f) {
  unsigned int u = __float_as_uint(f);
  return (u + 0x7fffu + ((u >> 16) & 1u)) >> 16;   // RNE
}
__device__ __forceinline__ float bf2f(ushort_t u) {
  return __uint_as_float(((unsigned int)u) << 16);
}
__device__ __forceinline__ void pack4(ushort_t* dst, float x0, float x1,
                                      float x2, float x3) {
  uint2 v;
  v.x = f2bf_u(x0) | (f2bf_u(x1) << 16);
  v.y = f2bf_u(x2) | (f2bf_u(x3) << 16);
  *(uint2*)dst = v;
}
__device__ __forceinline__ void mlmerge(float& M, float& L, float m2, float l2) {
  float nm = fmaxf(M, m2);
  float ea = (M  <= -1e29f) ? 0.f : __expf(M - nm);
  float eb = (m2 <= -1e29f) ? 0.f : __expf(m2 - nm);
  L = L * ea + l2 * eb;
  M = nm;
}

// Quad e-phase: 128 threads, each computes 4 cells of ep[tc][scell].
#define EPHASE(HQARR, HKARR, SSUM) do {                                      \
  if (tid < 128) {                                                           \
    const int tcq = tid >> 3, sq = tid & 7;                                  \
    const int sob = (s1 - sbeg) + sq*4;                                      \
    float a4[4] = {0.f,0.f,0.f,0.f}, b4[4] = {0.f,0.f,0.f,0.f};              \
    _Pragma("unroll")                                                        \
    for (int hq4 = 0; hq4 < 4; hq4++) {                                      \
      float hqa[4];                                                          \
      *(float4*)hqa = *(const float4*)&HQARR[tcq*16 + hq4*4];                \
      float hka[4][4];                                                       \
      _Pragma("unroll")                                                      \
      for (int c = 0; c < 4; c++)                                            \
        *(float4*)hka[c] = *(const float4*)&HKARR[(sob + c)*16 + hq4*4];     \
      _Pragma("unroll")                                                      \
      for (int j = 0; j < 4; j++) {                                          \
        const uint2 yr = *(const uint2*)                                     \
            &ybuf[((hq4*4 + j)*TQ + tcq)*PADS + sq*4];                       \
        float yv[4];                                                         \
        yv[0] = bf2f((ushort_t)(yr.x & 0xffffu));                            \
        yv[1] = bf2f((ushort_t)(yr.x >> 16));                                \
        yv[2] = bf2f((ushort_t)(yr.y & 0xffffu));                            \
        yv[3] = bf2f((ushort_t)(yr.y >> 16));                                \
        _Pragma("unroll")                                                    \
        for (int c = 0; c < 4; c++) {                                        \
          a4[c] += yv[c] * hqa[j];                                           \
          b4[c] += yv[c] * hka[c][j];                                        \
        }                                                                    \
      }                                                                      \
    }                                                                        \
    float ssum[4];                                                           \
    *(float4*)ssum = *(const float4*)&SSUM[sob];                             \
    float4 eo;                                                               \
    eo.x = a4[0]*(1.f + ssum[0]) + b4[0];                                    \
    eo.y = a4[1]*(1.f + ssum[1]) + b4[1];                                    \
    eo.z = a4[2]*(1.f + ssum[2]) + b4[2];                                    \
    eo.w = a4[3]*(1.f + ssum[3]) + b4[3];                                    \
    *(float4*)&ep[tcq*EPS + sq*4] = eo;                                      \
  }                                                                          \
} while (0)

// ---------------- 1. prep ----------------
__global__ __launch_bounds__(256) void prep_kernel(
    const float* __restrict__ x, const float* __restrict__ shift,
    const float* __restrict__ maa_x,
    float* __restrict__ dxprev, ushort_t* __restrict__ zbf,
    ushort_t* __restrict__ xbf)
{
  const int t = blockIdx.x;
  const int c = threadIdx.x * 4;
  const size_t base = (size_t)t * C_DIM + c;
  const float4 xc = *(const float4*)&x[base];
  const float4 xp = (t == 0) ? *(const float4*)&shift[c]
                             : *(const float4*)&x[base - C_DIM];
  const float4 mx = *(const float4*)&maa_x[c];
  float4 d;
  d.x = xp.x - xc.x; d.y = xp.y - xc.y; d.z = xp.z - xc.z; d.w = xp.w - xc.w;
  *(float4*)&dxprev[base] = d;
  pack4(&zbf[base], xc.x + d.x*mx.x, xc.y + d.y*mx.y,
        xc.z + d.z*mx.z, xc.w + d.w*mx.w);
  pack4(&xbf[base], xc.x, xc.y, xc.z, xc.w);
}

// ---------------- 2. lora weight prep ----------------
__global__ __launch_bounds__(256) void wlora_prep(
    const float* __restrict__ w1, const float* __restrict__ hw1,
    ushort_t* __restrict__ wlt)
{
  __shared__ float tile[32][33];
  const int k0 = blockIdx.x*32, j0 = blockIdx.y*32;
  const int r = threadIdx.x >> 3, c4 = (threadIdx.x & 7) * 4;
  const float* W = (j0 < 96) ? w1 : hw1;
  const int stride = (j0 < 96) ? 96 : 128;
  const int jo = (j0 < 96) ? j0 : j0 - 96;
  const float4 v = *(const float4*)&W[(size_t)(k0+r)*stride + jo + c4];
  tile[r][c4+0] = v.x; tile[r][c4+1] = v.y;
  tile[r][c4+2] = v.z; tile[r][c4+3] = v.w;
  __syncthreads();
  pack4(&wlt[(size_t)(j0+r)*C_DIM + k0 + c4],
        tile[c4+0][r], tile[c4+1][r], tile[c4+2][r], tile[c4+3][r]);
}

// ---------------- 3. lora GEMM with tanh epilogue ----------------
__global__ __launch_bounds__(64)
__attribute__((amdgpu_waves_per_eu(2, 4)))
void lora_gemm(
    const ushort_t* __restrict__ zbf, const ushort_t* __restrict__ xbf,
    const ushort_t* __restrict__ wlt, float* __restrict__ xxx,
    float* __restrict__ ha)
{
  const int nt = blockIdx.y;
  const int bm = blockIdx.x * 32;
  const ushort_t* A = (nt < 3) ? zbf : xbf;
  const int wrow = nt * 32;
  const int lane = threadIdx.x;
  const int l15 = lane & 15, g = lane >> 4;
  f32x4 acc[2][2];
  #pragma unroll
  for (int i = 0; i < 2; i++)
    #pragma unroll
    for (int j = 0; j < 2; j++) acc[i][j] = (f32x4){0.f,0.f,0.f,0.f};
  bf16x8 a0[2], b0[2], a1[2], b1[2];
  #define LLA(dst, kk) { \
    dst[0] = *(const bf16x8*)&A[(size_t)(bm + l15)*C_DIM + (kk) + g*8]; \
    dst[1] = *(const bf16x8*)&A[(size_t)(bm + 16 + l15)*C_DIM + (kk) + g*8]; }
  #define LLB(dst, kk) { \
    dst[0] = *(const bf16x8*)&wlt[(size_t)(wrow + l15)*C_DIM + (kk) + g*8]; \
    dst[1] = *(const bf16x8*)&wlt[(size_t)(wrow + 16 + l15)*C_DIM + (kk) + g*8]; }
  LLA(a0, 0); LLB(b0, 0);
  for (int k0 = 0; k0 < C_DIM; k0 += 64) {
    LLA(a1, k0+32); LLB(b1, k0+32);
    #pragma unroll
    for (int i = 0; i < 2; i++)
      #pragma unroll
      for (int j = 0; j < 2; j++) acc[i][j] = MFMA16(a0[i], b0[j], acc[i][j]);
    if (k0 + 64 < C_DIM) { LLA(a0, k0+64); LLB(b0, k0+64); }
    #pragma unroll
    for (int i = 0; i < 2; i++)
      #pragma unroll
      for (int j = 0; j < 2; j++) acc[i][j] = MFMA16(a1[i], b1[j], acc[i][j]);
  }
  #undef LLA
  #undef LLB
  #pragma unroll
  for (int i = 0; i < 2; i++)
    #pragma unroll
    for (int j = 0; j < 2; j++)
      #pragma unroll
      for (int r = 0; r < 4; r++) {
        const int t = bm + i*16 + g*4 + r;
        const int col = wrow + j*16 + l15;
        const float val = tanhf(acc[i][j][r]);
        if (nt < 3) xxx[(size_t)t*96 + col] = val;
        else        ha[(size_t)t*128 + col - 96] = val;
      }
}

// ---------------- 4. mix ----------------
__global__ __launch_bounds__(256) void mix_kernel(
    const float* __restrict__ x, const float* __restrict__ dxp,
    const float* __restrict__ xxx,
    const float* __restrict__ maa_r, const float* __restrict__ maa_k,
    const float* __restrict__ maa_v, const float* __restrict__ w2,
    ushort_t* __restrict__ xq, ushort_t* __restrict__ xk,
    ushort_t* __restrict__ xv)
{
  __shared__ float xs[8][96];
  const int t0 = blockIdx.x * 8;
  const int tid = threadIdx.x;
  #pragma unroll
  for (int i = 0; i < 3; i++) {
    const int u = tid + i*256;
    if (u < 768) {
      const int r = u / 96, cc = u % 96;
      xs[r][cc] = xxx[(size_t)(t0+r)*96 + cc];
    }
  }
  __syncthreads();
  const int c = tid * 4;
  float4 xc[8], dx[8];
  #pragma unroll
  for (int r = 0; r < 8; r++) {
    xc[r] = *(const float4*)&x[(size_t)(t0+r)*C_DIM + c];
    dx[r] = *(const float4*)&dxp[(size_t)(t0+r)*C_DIM + c];
  }
  const float* maas[3] = {maa_r, maa_k, maa_v};
  ushort_t* outs[3] = {xq, xk, xv};
  #pragma unroll
  for (int n = 0; n < 3; n++) {
    const float4 mv = *(const float4*)&maas[n][c];
    float m[8][4];
    #pragma unroll
    for (int r = 0; r < 8; r++) {
      m[r][0] = mv.x; m[r][1] = mv.y; m[r][2] = mv.z; m[r][3] = mv.w;
    }
    #pragma unroll 8
    for (int d = 0; d < 32; d++) {
      const float4 w = *(const float4*)&w2[((size_t)n*32 + d)*C_DIM + c];
      #pragma unroll
      for (int r = 0; r < 8; r++) {
        const float xv2 = xs[r][n*32 + d];
        m[r][0] += xv2*w.x; m[r][1] += xv2*w.y;
        m[r][2] += xv2*w.z; m[r][3] += xv2*w.w;
      }
    }
    #pragma unroll
    for (int r = 0; r < 8; r++)
      pack4(&outs[n][(size_t)(t0+r)*C_DIM + c],
            xc[r].x + dx[r].x*m[r][0], xc[r].y + dx[r].y*m[r][1],
            xc[r].z + dx[r].z*m[r][2], xc[r].w + dx[r].w*m[r][3]);
  }
}

// ---------------- 5. hm ----------------
__global__ __launch_bounds__(256) void hm_kernel(
    const float* __restrict__ ha, const float* __restrict__ hw2,
    float* __restrict__ hm, int T)
{
  const int t = blockIdx.x*4 + (threadIdx.x >> 6);
  const int u = threadIdx.x & 63;
  const int n = u >> 4, h = u & 15;
  float s = 0.f;
  #pragma unroll 8
  for (int d = 0; d < 32; d++)
    s += ha[(size_t)t*128 + n*32 + d] * hw2[(size_t)(n*32 + d)*16 + h];
  hm[((size_t)n*T + t)*16 + h] = s * (1.f/16.f);
}

// ---------------- 6. weight prep ----------------
__global__ __launch_bounds__(256) void wprep_kernel(
    const float* __restrict__ w0, const float* __restrict__ w1,
    const float* __restrict__ w2, const float* __restrict__ w3,
    ushort_t* __restrict__ o0, ushort_t* __restrict__ o1,
    ushort_t* __restrict__ o2, ushort_t* __restrict__ o3)
{
  const float* W; ushort_t* O;
  if (blockIdx.z == 0)      { W = w0; O = o0; }
  else if (blockIdx.z == 1) { W = w1; O = o1; }
  else if (blockIdx.z == 2) { W = w2; O = o2; }
  else                      { W = w3; O = o3; }
  __shared__ float tile[32][33];
  const int k0 = blockIdx.x*32, n0 = blockIdx.y*32;
  const int r = threadIdx.x >> 3, c4 = (threadIdx.x & 7) * 4;
  const float4 v = *(const float4*)&W[(size_t)(k0+r)*C_DIM + n0 + c4];
  tile[r][c4+0] = v.x; tile[r][c4+1] = v.y;
  tile[r][c4+2] = v.z; tile[r][c4+3] = v.w;
  __syncthreads();
  pack4(&O[(size_t)(n0+r)*C_DIM + k0 + c4],
        tile[c4+0][r], tile[c4+1][r], tile[c4+2][r], tile[c4+3][r]);
}

// ---------------- 7. bf16 MFMA GEMM ----------------
__global__ __launch_bounds__(64)
__attribute__((amdgpu_waves_per_eu(2, 4)))
void gemm_bf16(
    const ushort_t* __restrict__ A, const ushort_t* __restrict__ Bt,
    float* __restrict__ Cm)
{
  const int bid = blockIdx.x;
  const int bn = (bid & 15) * 64;
  const int bm = (bid >> 4) * 32;
  const int lane = threadIdx.x;
  const int l15 = lane & 15, g = lane >> 4;
  f32x4 acc[2][4];
  #pragma unroll
  for (int i = 0; i < 2; i++)
    #pragma unroll
    for (int j = 0; j < 4; j++) acc[i][j] = (f32x4){0.f,0.f,0.f,0.f};
  bf16x8 a0[2], b0[4], a1[2], b1[4];
  #define LGA(dst, kk) { \
    _Pragma("unroll") \
    for (int i = 0; i < 2; i++) \
      dst[i] = *(const bf16x8*)&A[(size_t)(bm + i*16 + l15)*C_DIM + (kk) + g*8]; }
  #define LGB(dst, kk) { \
    _Pragma("unroll") \
    for (int j = 0; j < 4; j++) \
      dst[j] = *(const bf16x8*)&Bt[(size_t)(bn + j*16 + l15)*C_DIM + (kk) + g*8]; }
  LGA(a0, 0); LGB(b0, 0);
  for (int k0 = 0; k0 < C_DIM; k0 += 64) {
    LGA(a1, k0+32); LGB(b1, k0+32);
    #pragma unroll
    for (int i = 0; i < 2; i++)
      #pragma unroll
      for (int j = 0; j < 4; j++) acc[i][j] = MFMA16(a0[i], b0[j], acc[i][j]);
    if (k0 + 64 < C_DIM) { LGA(a0, k0+64); LGB(b0, k0+64); }
    #pragma unroll
    for (int i = 0; i < 2; i++)
      #pragma unroll
      for (int j = 0; j < 4; j++) acc[i][j] = MFMA16(a1[i], b1[j], acc[i][j]);
  }
  #undef LGA
  #undef LGB
  #pragma unroll
  for (int i = 0; i < 2; i++)
    #pragma unroll
    for (int j = 0; j < 4; j++)
      #pragma unroll
      for (int r = 0; r < 4; r++)
        Cm[(size_t)(bm + i*16 + g*4 + r)*C_DIM + bn + j*16 + l15] = acc[i][j][r];
}

// ---------------- 8. row LayerNorm -> bf16 ----------------
__global__ __launch_bounds__(256) void ln_rows(
    const float* __restrict__ in, ushort_t* __restrict__ outp,
    const float* __restrict__ g, const float* __restrict__ b, float scale)
{
  __shared__ float red[4];
  const int t = blockIdx.x;
  const int tid = threadIdx.x;
  const int c = tid*4;
  const float4 v = *(const float4*)&in[(size_t)t*C_DIM + c];
  float s = v.x+v.y+v.z+v.w;
  #pragma unroll
  for (int off = 32; off > 0; off >>= 1) s += __shfl_down(s, off, 64);
  if ((tid & 63) == 0) red[tid >> 6] = s;
  __syncthreads();
  const float mean = (red[0]+red[1]+red[2]+red[3]) * (1.0f/C_DIM);
  __syncthreads();
  const float d0 = v.x-mean, d1 = v.y-mean, d2 = v.z-mean, d3 = v.w-mean;
  float q = d0*d0 + d1*d1 + d2*d2 + d3*d3;
  #pragma unroll
  for (int off = 32; off > 0; off >>= 1) q += __shfl_down(q, off, 64);
  if ((tid & 63) == 0) red[tid >> 6] = q;
  __syncthreads();
  const float var = (red[0]+red[1]+red[2]+red[3]) * (1.0f/C_DIM);
  const float rstd = rsqrtf(var + 1e-5f);
  const float4 gv = *(const float4*)&g[c];
  const float4 bv = *(const float4*)&b[c];
  pack4(outp + (size_t)t*C_DIM + c,
        (d0*rstd*gv.x + bv.x)*scale, (d1*rstd*gv.y + bv.y)*scale,
        (d2*rstd*gv.z + bv.z)*scale, (d3*rstd*gv.w + bv.w)*scale);
}

// ---------------- 9. V transpose ----------------
__global__ __launch_bounds__(256) void vtrans_kernel(
    const ushort_t* __restrict__ vbf, ushort_t* __restrict__ Vt, int T)
{
  __shared__ ushort_t tile[32][36];
  const int t0 = blockIdx.x*32, c0 = blockIdx.y*32;
  const int r = threadIdx.x >> 3, c4 = (threadIdx.x & 7) * 4;
  const uint2 raw = *(const uint2*)&vbf[(size_t)(t0+r)*C_DIM + c0 + c4];
  tile[r][c4+0] = (ushort_t)(raw.x & 0xffffu);
  tile[r][c4+1] = (ushort_t)(raw.x >> 16);
  tile[r][c4+2] = (ushort_t)(raw.y & 0xffffu);
  tile[r][c4+3] = (ushort_t)(raw.y >> 16);
  __syncthreads();
  uint2 w;
  w.x = (unsigned)tile[c4+0][r] | ((unsigned)tile[c4+1][r] << 16);
  w.y = (unsigned)tile[c4+2][r] | ((unsigned)tile[c4+3][r] << 16);
  *(uint2*)&Vt[(size_t)(c0+r)*T + t0 + c4] = w;
}

// ---------------- 10. attention phase A: softmax stats (balanced sc) -------
__global__ __launch_bounds__(512)
__attribute__((amdgpu_waves_per_eu(2, 4)))
void attn_stats(
    const ushort_t* __restrict__ qbf, const ushort_t* __restrict__ kbf,
    const float* __restrict__ hmb, float* __restrict__ part_m,
    float* __restrict__ part_l, int T)
{
  __shared__ ushort_t ybuf[HEADS*TQ*PADS];
  __shared__ float ep[TQ*EPS];
  __shared__ float hpqf[TQ*16];
  __shared__ float hpkf[SCH*16];
  __shared__ float spk_l[SCH];

  const int tbi = (int)blockIdx.y;
  const int tb = (T/TQ) - 1 - tbi;                 // longest-first
  const int sc = ((int)blockIdx.x + tbi) & 7;      // balanced across XCDs
  const int t0 = tb * TQ;
  const int sbeg = sc * SCH;
  if (sbeg >= t0 + TQ) return;
  const int send = (sbeg + SCH < t0 + TQ) ? (sbeg + SCH) : (t0 + TQ);

  const int tid = threadIdx.x;
  const int w = tid >> 6, lane = tid & 63, l15 = lane & 15, g = lane >> 4;

  for (int i = tid; i < SCH*16; i += 512)
    hpkf[i] = hmb[((size_t)1*T + sbeg)*16 + i];
  if (tid < TQ*16)
    hpqf[tid] = hmb[((size_t)0*T + t0)*16 + tid];
  if (tid < SCH) {
    const float* src = hmb + ((size_t)1*T + sbeg + tid)*16;
    float s = 0.f;
    #pragma unroll
    for (int q4 = 0; q4 < 4; q4++) {
      const float4 v = *(const float4*)&src[q4*4];
      s += v.x + v.y + v.z + v.w;
    }
    spk_l[tid] = s;
  }

  const int hh[2] = {w, w + 8};
  bf16x8 qf[2][2];
  float slope[2];
  #pragma unroll
  for (int hd = 0; hd < 2; hd++) {
    #pragma unroll
    for (int kc = 0; kc < 2; kc++)
      qf[hd][kc] = *(const bf16x8*)
          &qbf[(size_t)(t0 + l15)*C_DIM + hh[hd]*64 + kc*32 + g*8];
    slope[hd] = exp2f(-0.5f * (float)(hh[hd] + 1));
  }
  float mrun[2] = {-1e30f, -1e30f}, lrun[2] = {0.f, 0.f};

  bf16x8 kf[2][2][2];
  #define LOADK(sbase) { \
    _Pragma("unroll") \
    for (int hd = 0; hd < 2; hd++) \
      _Pragma("unroll") \
      for (int sh = 0; sh < 2; sh++) \
        _Pragma("unroll") \
        for (int kc = 0; kc < 2; kc++) \
          kf[hd][sh][kc] = *(const bf16x8*)&kbf[ \
              (size_t)((sbase) + sh*16 + l15)*C_DIM + hh[hd]*64 + kc*32 + g*8]; }
  LOADK(sbeg);

  for (int s1 = sbeg; s1 < send; s1 += 32) {
    f32x4 acc[2][2];
    #pragma unroll
    for (int hd = 0; hd < 2; hd++)
      #pragma unroll
      for (int sh = 0; sh < 2; sh++) acc[hd][sh] = (f32x4){0.f,0.f,0.f,0.f};
    #pragma unroll
    for (int hd = 0; hd < 2; hd++) {
      #pragma unroll
      for (int sh = 0; sh < 2; sh++)
        #pragma unroll
        for (int kc = 0; kc < 2; kc++)
          acc[hd][sh] = MFMA16(kf[hd][sh][kc], qf[hd][kc], acc[hd][sh]);
      #pragma unroll
      for (int sh = 0; sh < 2; sh++)
        pack4(&ybuf[(size_t)(hh[hd]*TQ + l15)*PADS + sh*16 + g*4],
              acc[hd][sh][0], acc[hd][sh][1], acc[hd][sh][2], acc[hd][sh][3]);
    }
    {
      const int snx = (s1 + 32 < send) ? s1 + 32 : s1;
      LOADK(snx);
    }
    __syncthreads();
    EPHASE(hpqf, hpkf, spk_l);
    __syncthreads();
    float epv[2][4];
    #pragma unroll
    for (int sh = 0; sh < 2; sh++)
      *(float4*)epv[sh] = *(const float4*)&ep[l15*EPS + sh*16 + g*4];
    #pragma unroll
    for (int hd = 0; hd < 2; hd++) {
      const int t = t0 + l15;
      #pragma unroll
      for (int sh = 0; sh < 2; sh++)
        #pragma unroll
        for (int r = 0; r < 4; r++) {
          const int s = s1 + sh*16 + g*4 + r;
          if (s <= t) {
            const float y3 = acc[hd][sh][r] + epv[sh][r]
                - slope[hd]*(float)(t - s);
            const float d = y3 - mrun[hd];
            if (d > 0.f) { lrun[hd] = lrun[hd]*__expf(-d) + 1.f; mrun[hd] = y3; }
            else lrun[hd] += __expf(d);
          }
        }
    }
  }
  #undef LOADK
  #pragma unroll
  for (int hd = 0; hd < 2; hd++) {
    float M = mrun[hd], L = lrun[hd];
    #pragma unroll
    for (int mask = 16; mask < 64; mask <<= 1) {
      const float M2 = __shfl_xor(M, mask, 64);
      const float L2 = __shfl_xor(L, mask, 64);
      mlmerge(M, L, M2, L2);
    }
    if (g == 0) {
      part_m[(size_t)(sc*HEADS + hh[hd])*T + t0 + l15] = M;
      part_l[(size_t)(sc*HEADS + hh[hd])*T + t0 + l15] = L;
    }
  }
}

// ---------------- 11. merge partial (m,l) ----------------
__global__ __launch_bounds__(256) void ml_combine(
    const float* __restrict__ part_m, const float* __restrict__ part_l,
    float* __restrict__ m_fin, float* __restrict__ linv, int T)
{
  const int idx = blockIdx.x*256 + threadIdx.x;   // h*T + t
  const int t = idx & (T - 1);
  const int nsc = (t >> 8) + 1;
  float M = -1e30f, L = 0.f;
  for (int sc = 0; sc < nsc; sc++)
    mlmerge(M, L, part_m[(size_t)sc*HEADS*T + idx],
            part_l[(size_t)sc*HEADS*T + idx]);
  m_fin[idx] = M;
  linv[idx] = 1.f / L;
}

// ---------------- 12. attention phase B: apply (template, balanced sc) -----
// MODE 0: full.  MODE 1: no e-phases, NO barriers (wave-independent probe).
// MODE 5: barriers kept, e-phases replaced by constant writes (probe).
template<int MODE>
__global__ __launch_bounds__(512)
__attribute__((amdgpu_waves_per_eu(2, 4)))
void attn_apply(
    const ushort_t* __restrict__ qbf, const ushort_t* __restrict__ kbf,
    const ushort_t* __restrict__ Vt, const float* __restrict__ hmb,
    const float* __restrict__ m_fin, const float* __restrict__ linv,
    float* __restrict__ P, int T)
{
  __shared__ ushort_t ybuf[HEADS*TQ*PADS];
  __shared__ float ep[TQ*EPS];
  __shared__ float hpqf[TQ*16], hoqf[TQ*16];
  __shared__ float hpkf[SCH*16], hokf[SCH*16];
  __shared__ float spk_l[SCH], spo_l[SCH];

  const int tbi = (int)blockIdx.y & (128 - 1);     // works for 1x and 2x grids
  const int tb = (T/TQ) - 1 - tbi;
  const int sc = ((int)blockIdx.x + tbi) & 7;      // balanced across XCDs
  const int t0 = tb * TQ;
  const int sbeg = sc * SCH;
  if (sbeg >= t0 + TQ) return;
  const int send = (sbeg + SCH < t0 + TQ) ? (sbeg + SCH) : (t0 + TQ);
  const int prow0 = T*sc - 128*sc*(sc-1) - SCH*sc;

  const int tid = threadIdx.x;
  const int w = tid >> 6, lane = tid & 63, l15 = lane & 15, g = lane >> 4;

  if (MODE != 1) {
    for (int i = tid; i < SCH*16; i += 512) {
      hpkf[i] = hmb[((size_t)1*T + sbeg)*16 + i];
      hokf[i] = hmb[((size_t)3*T + sbeg)*16 + i];
    }
    if (tid < TQ*16) {
      hpqf[tid] = hmb[((size_t)0*T + t0)*16 + tid];
      hoqf[tid] = hmb[((size_t)2*T + t0)*16 + tid];
    }
    {
      const int s_l = tid & 255;
      const float* src = hmb + ((size_t)((tid < 256) ? 1 : 3)*T + sbeg + s_l)*16;
      float s = 0.f;
      #pragma unroll
      for (int q4 = 0; q4 < 4; q4++) {
        const float4 v = *(const float4*)&src[q4*4];
        s += v.x + v.y + v.z + v.w;
      }
      if (tid < 256) spk_l[s_l] = s; else spo_l[s_l] = s;
    }
  }

  const int hh[2] = {w, w + 8};
  bf16x8 qf[2][2];
  float mt[2], li[2], slope[2];
  #pragma unroll
  for (int hd = 0; hd < 2; hd++) {
    #pragma unroll
    for (int kc = 0; kc < 2; kc++)
      qf[hd][kc] = *(const bf16x8*)
          &qbf[(size_t)(t0 + l15)*C_DIM + hh[hd]*64 + kc*32 + g*8];
    mt[hd] = m_fin[(size_t)hh[hd]*T + t0 + l15];
    li[hd] = linv[(size_t)hh[hd]*T + t0 + l15];
    slope[hd] = exp2f(-0.5f * (float)(hh[hd] + 1));
  }
  f32x4 oacc[2][4];
  #pragma unroll
  for (int hd = 0; hd < 2; hd++)
    #pragma unroll
    for (int vf = 0; vf < 4; vf++) oacc[hd][vf] = (f32x4){0.f,0.f,0.f,0.f};

  for (int s1 = sbeg; s1 < send; s1 += 32) {
    f32x4 acc[2][2];
    #pragma unroll
    for (int hd = 0; hd < 2; hd++)
      #pragma unroll
      for (int sh = 0; sh < 2; sh++) acc[hd][sh] = (f32x4){0.f,0.f,0.f,0.f};
    #pragma unroll
    for (int hd = 0; hd < 2; hd++) {
      #pragma unroll
      for (int sh = 0; sh < 2; sh++)
        #pragma unroll
        for (int kc = 0; kc < 2; kc++) {
          const bf16x8 kf = *(const bf16x8*)
              &kbf[(size_t)(s1 + sh*16 + l15)*C_DIM + hh[hd]*64 + kc*32 + g*8];
          acc[hd][sh] = MFMA16(kf, qf[hd][kc], acc[hd][sh]);
        }
      if (MODE != 1) {
        #pragma unroll
        for (int sh = 0; sh < 2; sh++)
          pack4(&ybuf[(size_t)(hh[hd]*TQ + l15)*PADS + sh*16 + g*4],
                acc[hd][sh][0], acc[hd][sh][1], acc[hd][sh][2], acc[hd][sh][3]);
      }
    }
    if (MODE != 1) __syncthreads();              // bar1: y0 ready
    if (MODE == 0) {
      EPHASE(hpqf, hpkf, spk_l);
    } else if (MODE == 5) {
      if (tid < 128) {
        const int tcq = tid >> 3, sq = tid & 7;
        *(float4*)&ep[tcq*EPS + sq*4] =
            make_float4(0.03125f, 0.03125f, 0.03125f, 0.03125f);
      }
    }
    if (MODE != 1) __syncthreads();              // bar2: ep ready; ybuf free
    {
      float epv[2][4];
      if (MODE != 1) {
        #pragma unroll
        for (int sh = 0; sh < 2; sh++)
          *(float4*)epv[sh] = *(const float4*)&ep[l15*EPS + sh*16 + g*4];
      } else {
        #pragma unroll
        for (int sh = 0; sh < 2; sh++)
          #pragma unroll
          for (int r = 0; r < 4; r++) epv[sh][r] = 0.f;
      }
      #pragma unroll
      for (int hd = 0; hd < 2; hd++) {
        const int t = t0 + l15;
        #pragma unroll
        for (int sh = 0; sh < 2; sh++) {
          #pragma unroll
          for (int r = 0; r < 4; r++) {
            const int s = s1 + sh*16 + g*4 + r;
            float p = 0.f;
            if (s <= t) {
              const float y3 = acc[hd][sh][r] + epv[sh][r]
                  - slope[hd]*(float)(t - s);
              p = __expf(y3 - mt[hd]) * li[hd];
            }
            acc[hd][sh][r] = p;
          }
          if (MODE != 1)
            pack4(&ybuf[(size_t)(hh[hd]*TQ + l15)*PADS + sh*16 + g*4],
                  acc[hd][sh][0], acc[hd][sh][1], acc[hd][sh][2],
                  acc[hd][sh][3]);
        }
      }
    }
    if (MODE != 1) __syncthreads();              // bar3: p ready
    if (MODE == 0) {
      EPHASE(hoqf, hokf, spo_l);
    } else if (MODE == 5) {
      if (tid < 128) {
        const int tcq = tid >> 3, sq = tid & 7;
        *(float4*)&ep[tcq*EPS + sq*4] =
            make_float4(0.03125f, 0.03125f, 0.03125f, 0.03125f);
      }
    }
    if (MODE != 1) __syncthreads();              // bar4: ep2 ready
    bf16x8 vv[2][4];
    #pragma unroll
    for (int hd = 0; hd < 2; hd++)
      #pragma unroll
      for (int vf = 0; vf < 4; vf++)
        vv[hd][vf] = *(const bf16x8*)
            &Vt[(size_t)(hh[hd]*64 + vf*16 + l15)*T + s1 + g*8];
    {
      float epv[2][4];
      if (MODE != 1) {
        #pragma unroll
        for (int sh = 0; sh < 2; sh++)
          *(float4*)epv[sh] = *(const float4*)&ep[l15*EPS + sh*16 + g*4];
      } else {
        #pragma unroll
        for (int sh = 0; sh < 2; sh++)
          #pragma unroll
          for (int r = 0; r < 4; r++) epv[sh][r] = 0.f;
      }
      #pragma unroll
      for (int hd = 0; hd < 2; hd++)
        #pragma unroll
        for (int sh = 0; sh < 2; sh++)
          pack4(&ybuf[(size_t)(hh[hd]*TQ + l15)*PADS + sh*16 + g*4],
                acc[hd][sh][0] + epv[sh][0], acc[hd][sh][1] + epv[sh][1],
                acc[hd][sh][2] + epv[sh][2], acc[hd][sh][3] + epv[sh][3]);
    }
    #pragma unroll
    for (int hd = 0; hd < 2; hd++) {
      const bf16x8 pa = *(const bf16x8*)
          &ybuf[(size_t)(hh[hd]*TQ + l15)*PADS + g*8];
      #pragma unroll
      for (int vf = 0; vf < 4; vf++)
        oacc[hd][vf] = MFMA16(pa, vv[hd][vf], oacc[hd][vf]);
    }
  }
  #pragma unroll
  for (int hd = 0; hd < 2; hd++)
    #pragma unroll
    for (int vf = 0; vf < 4; vf++)
      #pragma unroll
      for (int r = 0; r < 4; r++)
        P[(size_t)(prow0 + t0 + g*4 + r)*C_DIM + hh[hd]*64 + vf*16 + l15]
            = oacc[hd][vf][r];
}

// ---------------- 13. reduce partials + LayerNorm -> bf16 ----------------
__global__ __launch_bounds__(256) void reduce_ln(
    const float* __restrict__ P, ushort_t* __restrict__ outp,
    const float* __restrict__ g, const float* __restrict__ b, int T)
{
  __shared__ float red[4];
  const int t = blockIdx.x;
  const int tid = threadIdx.x;
  const int c = tid*4;
  const int nsc = (t >> 8) + 1;
  float4 v = make_float4(0.f, 0.f, 0.f, 0.f);
  int off = 0;
  for (int sc = 0; sc < nsc; sc++) {
    const int row = off + t - sc*SCH;
    const float4 pv = *(const float4*)&P[(size_t)row*C_DIM + c];
    v.x += pv.x; v.y += pv.y; v.z += pv.z; v.w += pv.w;
    off += T - SCH*sc;
  }
  float s = v.x+v.y+v.z+v.w;
  #pragma unroll
  for (int o = 32; o > 0; o >>= 1) s += __shfl_down(s, o, 64);
  if ((tid & 63) == 0) red[tid >> 6] = s;
  __syncthreads();
  const float mean = (red[0]+red[1]+red[2]+red[3]) * (1.0f/C_DIM);
  __syncthreads();
  const float d0 = v.x-mean, d1 = v.y-mean, d2 = v.z-mean, d3 = v.w-mean;
  float q = d0*d0 + d1*d1 + d2*d2 + d3*d3;
  #pragma unroll
  for (int o = 32; o > 0; o >>= 1) q += __shfl_down(q, o, 64);
  if ((tid & 63) == 0) red[tid >> 6] = q;
  __syncthreads();
  const float var = (red[0]+red[1]+red[2]+red[3]) * (1.0f/C_DIM);
  const float rstd = rsqrtf(var + 1e-5f);
  const float4 gv = *(const float4*)&g[c];
  const float4 bv = *(const float4*)&b[c];
  pack4(outp + (size_t)t*C_DIM + c,
        d0*rstd*gv.x + bv.x, d1*rstd*gv.y + bv.y,
        d2*rstd*gv.z + bv.z, d3*rstd*gv.w + bv.w);
}

// ---------------- launcher ----------------
extern "C" void kernel_launch(void* const* d_in, const int* in_sizes, int n_in,
                              void* d_out, int out_size, void* d_ws, size_t ws_size,
                              hipStream_t stream)
{
  const float* x      = (const float*)d_in[0];
  const float* shift  = (const float*)d_in[1];
  const float* maa_x  = (const float*)d_in[2];
  const float* maa_r  = (const float*)d_in[3];
  const float* maa_k  = (const float*)d_in[4];
  const float* maa_v  = (const float*)d_in[5];
  const float* w1     = (const float*)d_in[6];
  const float* w2     = (const float*)d_in[7];
  const float* hw1    = (const float*)d_in[8];
  const float* hw2    = (const float*)d_in[9];
  const float* w_r    = (const float*)d_in[10];
  const float* w_k    = (const float*)d_in[11];
  const float* w_v    = (const float*)d_in[12];
  const float* w_o    = (const float*)d_in[13];
  const float* ln_r_g = (const float*)d_in[14];
  const float* ln_r_b = (const float*)d_in[15];
  const float* ln_k_g = (const float*)d_in[16];
  const float* ln_k_b = (const float*)d_in[17];
  const float* ln_v_g = (const float*)d_in[18];
  const float* ln_v_b = (const float*)d_in[19];
  const float* ln_x_g = (const float*)d_in[20];
  const float* ln_x_b = (const float*)d_in[21];

  const int T = in_sizes[0] / C_DIM;            // 2048
  const size_t MM = (size_t)T * C_DIM;          // 2M f32 elems
  const size_t HF = MM / 2;                     // bf16 tensor in f32 units

  float* ws = (float*)d_ws;
  float*    P      = ws;
  float*    dxprev = ws;                          // MM
  ushort_t* zbf    = (ushort_t*)(ws + MM);        // HF
  ushort_t* xbf    = (ushort_t*)(ws + MM + HF);   // HF
  float*    gtmp   = ws + 2*MM;                   // MM
  ushort_t* xqb    = (ushort_t*)(ws + 3*MM);      // HF
  ushort_t* xkb    = (ushort_t*)(ws + 3*MM + HF); // HF
  ushort_t* xvb    = (ushort_t*)(ws + 4*MM);      // HF
  float* base2 = ws + 4*MM + HF;                  // = 4.5*MM
  ushort_t* qbf = (ushort_t*)(base2 + 0*HF);
  ushort_t* kbf = (ushort_t*)(base2 + 1*HF);
  ushort_t* vbf = (ushort_t*)(base2 + 2*HF);
  ushort_t* Vt  = (ushort_t*)(base2 + 3*HF);
  ushort_t* wtr = (ushort_t*)(base2 + 4*HF);
  ushort_t* wtk = wtr + (size_t)C_DIM*C_DIM;
  ushort_t* wtv = wtk + (size_t)C_DIM*C_DIM;
  ushort_t* wto = wtv + (size_t)C_DIM*C_DIM;
  float* after_w = base2 + 4*HF + (size_t)2*C_DIM*C_DIM;
  ushort_t* wlt = (ushort_t*)after_w;
  float* xxx    = after_w + 131072;
  float* ha     = xxx + (size_t)T*96;
  float* hmb    = ha + (size_t)T*128;
  float* part_m = hmb + (size_t)4*T*16;
  float* part_l = part_m + (size_t)8*HEADS*T;
  float* m_fin  = part_l + (size_t)8*HEADS*T;
  float* linv   = m_fin + (size_t)HEADS*T;
  ushort_t* abf = (ushort_t*)(linv + (size_t)HEADS*T);

  prep_kernel<<<T, 256, 0, stream>>>(x, shift, maa_x, dxprev, zbf, xbf);
  wlora_prep<<<dim3(C_DIM/32, 7), 256, 0, stream>>>(w1, hw1, wlt);
  lora_gemm<<<dim3(T/32, 7), 64, 0, stream>>>(zbf, xbf, wlt, xxx, ha);
  mix_kernel<<<T/8, 256, 0, stream>>>(x, dxprev, xxx, maa_r, maa_k, maa_v, w2,
                                      xqb, xkb, xvb);
  hm_kernel<<<T/4, 256, 0, stream>>>(ha, hw2, hmb, T);
  wprep_kernel<<<dim3(32, 32, 4), 256, 0, stream>>>(
      w_r, w_k, w_v, w_o, wtr, wtk, wtv, wto);

  const int ggemm = (T/32) * (C_DIM/64);
  gemm_bf16<<<ggemm, 64, 0, stream>>>(xqb, wtr, gtmp);
  ln_rows<<<T, 256, 0, stream>>>(gtmp, qbf, ln_r_g, ln_r_b, 0.125f);
  gemm_bf16<<<ggemm, 64, 0, stream>>>(xkb, wtk, gtmp);
  ln_rows<<<T, 256, 0, stream>>>(gtmp, kbf, ln_k_g, ln_k_b, 1.0f);
  gemm_bf16<<<ggemm, 64, 0, stream>>>(xvb, wtv, gtmp);
  ln_rows<<<T, 256, 0, stream>>>(gtmp, vbf, ln_v_g, ln_v_b, 1.0f);
  vtrans_kernel<<<dim3(T/32, C_DIM/32), 256, 0, stream>>>(vbf, Vt, T);

  attn_stats<<<dim3(8, T/TQ), 512, 0, stream>>>(
      qbf, kbf, hmb, part_m, part_l, T);
  ml_combine<<<(HEADS*T)/256, 256, 0, stream>>>(part_m, part_l, m_fin, linv, T);

  // --- diagnostic probes (2x grid; garbage into P, overwritten by <0>) ---
  attn_apply<1><<<dim3(8, 2*(T/TQ)), 512, 0, stream>>>(
      qbf, kbf, Vt, hmb, m_fin, linv, P, T);
  attn_apply<5><<<dim3(8, 2*(T/TQ)), 512, 0, stream>>>(
      qbf, kbf, Vt, hmb, m_fin, linv, P, T);
  // --- real pass ---
  attn_apply<0><<<dim3(8, T/TQ), 512, 0, stream>>>(
      qbf, kbf, Vt, hmb, m_fin, linv, P, T);

  reduce_ln<<<T, 256, 0, stream>>>(P, abf, ln_x_g, ln_x_b, T);
  gemm_bf16<<<ggemm, 64, 0, stream>>>(abf, wto, (float*)d_out);
}

// Round 9
// 545.422 us; speedup vs baseline: 1.6825x; 1.6825x over previous
//
#include <hip/hip_runtime.h>
#include <cstdint>
#include <cstddef>

// RWKV_Tmix_headmixer — round 9: paired-pinned XCD mapping (balance+locality).
// sc = (tbi&1) ? 7-bid.x : bid.x  ->  XCD i serves chunks {i, 7-i}:
// equal work (144 tile-units each) AND 2MB K/V working set per XCD (L2-fit).
// Probes removed; everything else identical to R7.
// B=1, T=2048, C=1024, H=16, K=64.

#define C_DIM 1024
#define HEADS 16
#define TQ 16            // t rows per attention block
#define SCH 256          // s-chunk per block
#define PADS 40          // ybuf inner stride (bf16)
#define EPS 36           // ep f32 stride (16B-aligned rows)

typedef unsigned short ushort_t;
typedef __attribute__((ext_vector_type(8))) short bf16x8;
typedef __attribute__((ext_vector_type(4))) float f32x4;

#define MFMA16(a, b, c) __builtin_amdgcn_mfma_f32_16x16x32_bf16(a, b, c, 0, 0, 0)

__device__ __forceinline__ unsigned int f2bf_u(float f) {
  unsigned int u = __float_as_uint(f);
  return (u + 0x7fffu + ((u >> 16) & 1u)) >> 16;   // RNE
}
__device__ __forceinline__ float bf2f(ushort_t u) {
  return __uint_as_float(((unsigned int)u) << 16);
}
__device__ __forceinline__ void pack4(ushort_t* dst, float x0, float x1,
                                      float x2, float x3) {
  uint2 v;
  v.x = f2bf_u(x0) | (f2bf_u(x1) << 16);
  v.y = f2bf_u(x2) | (f2bf_u(x3) << 16);
  *(uint2*)dst = v;
}
__device__ __forceinline__ void mlmerge(float& M, float& L, float m2, float l2) {
  float nm = fmaxf(M, m2);
  float ea = (M  <= -1e29f) ? 0.f : __expf(M - nm);
  float eb = (m2 <= -1e29f) ? 0.f : __expf(m2 - nm);
  L = L * ea + l2 * eb;
  M = nm;
}

// Quad e-phase: 128 threads, each computes 4 cells of ep[tc][scell].
#define EPHASE(HQARR, HKARR, SSUM) do {                                      \
  if (tid < 128) {                                                           \
    const int tcq = tid >> 3, sq = tid & 7;                                  \
    const int sob = (s1 - sbeg) + sq*4;                                      \
    float a4[4] = {0.f,0.f,0.f,0.f}, b4[4] = {0.f,0.f,0.f,0.f};              \
    _Pragma("unroll")                                                        \
    for (int hq4 = 0; hq4 < 4; hq4++) {                                      \
      float hqa[4];                                                          \
      *(float4*)hqa = *(const float4*)&HQARR[tcq*16 + hq4*4];                \
      float hka[4][4];                                                       \
      _Pragma("unroll")                                                      \
      for (int c = 0; c < 4; c++)                                            \
        *(float4*)hka[c] = *(const float4*)&HKARR[(sob + c)*16 + hq4*4];     \
      _Pragma("unroll")                                                      \
      for (int j = 0; j < 4; j++) {                                          \
        const uint2 yr = *(const uint2*)                                     \
            &ybuf[((hq4*4 + j)*TQ + tcq)*PADS + sq*4];                       \
        float yv[4];                                                         \
        yv[0] = bf2f((ushort_t)(yr.x & 0xffffu));                            \
        yv[1] = bf2f((ushort_t)(yr.x >> 16));                                \
        yv[2] = bf2f((ushort_t)(yr.y & 0xffffu));                            \
        yv[3] = bf2f((ushort_t)(yr.y >> 16));                                \
        _Pragma("unroll")                                                    \
        for (int c = 0; c < 4; c++) {                                        \
          a4[c] += yv[c] * hqa[j];                                           \
          b4[c] += yv[c] * hka[c][j];                                        \
        }                                                                    \
      }                                                                      \
    }                                                                        \
    float ssum[4];                                                           \
    *(float4*)ssum = *(const float4*)&SSUM[sob];                             \
    float4 eo;                                                               \
    eo.x = a4[0]*(1.f + ssum[0]) + b4[0];                                    \
    eo.y = a4[1]*(1.f + ssum[1]) + b4[1];                                    \
    eo.z = a4[2]*(1.f + ssum[2]) + b4[2];                                    \
    eo.w = a4[3]*(1.f + ssum[3]) + b4[3];                                    \
    *(float4*)&ep[tcq*EPS + sq*4] = eo;                                      \
  }                                                                          \
} while (0)

// ---------------- 1. prep ----------------
__global__ __launch_bounds__(256) void prep_kernel(
    const float* __restrict__ x, const float* __restrict__ shift,
    const float* __restrict__ maa_x,
    float* __restrict__ dxprev, ushort_t* __restrict__ zbf,
    ushort_t* __restrict__ xbf)
{
  const int t = blockIdx.x;
  const int c = threadIdx.x * 4;
  const size_t base = (size_t)t * C_DIM + c;
  const float4 xc = *(const float4*)&x[base];
  const float4 xp = (t == 0) ? *(const float4*)&shift[c]
                             : *(const float4*)&x[base - C_DIM];
  const float4 mx = *(const float4*)&maa_x[c];
  float4 d;
  d.x = xp.x - xc.x; d.y = xp.y - xc.y; d.z = xp.z - xc.z; d.w = xp.w - xc.w;
  *(float4*)&dxprev[base] = d;
  pack4(&zbf[base], xc.x + d.x*mx.x, xc.y + d.y*mx.y,
        xc.z + d.z*mx.z, xc.w + d.w*mx.w);
  pack4(&xbf[base], xc.x, xc.y, xc.z, xc.w);
}

// ---------------- 2. lora weight prep ----------------
__global__ __launch_bounds__(256) void wlora_prep(
    const float* __restrict__ w1, const float* __restrict__ hw1,
    ushort_t* __restrict__ wlt)
{
  __shared__ float tile[32][33];
  const int k0 = blockIdx.x*32, j0 = blockIdx.y*32;
  const int r = threadIdx.x >> 3, c4 = (threadIdx.x & 7) * 4;
  const float* W = (j0 < 96) ? w1 : hw1;
  const int stride = (j0 < 96) ? 96 : 128;
  const int jo = (j0 < 96) ? j0 : j0 - 96;
  const float4 v = *(const float4*)&W[(size_t)(k0+r)*stride + jo + c4];
  tile[r][c4+0] = v.x; tile[r][c4+1] = v.y;
  tile[r][c4+2] = v.z; tile[r][c4+3] = v.w;
  __syncthreads();
  pack4(&wlt[(size_t)(j0+r)*C_DIM + k0 + c4],
        tile[c4+0][r], tile[c4+1][r], tile[c4+2][r], tile[c4+3][r]);
}

// ---------------- 3. lora GEMM with tanh epilogue ----------------
__global__ __launch_bounds__(64)
__attribute__((amdgpu_waves_per_eu(2, 4)))
void lora_gemm(
    const ushort_t* __restrict__ zbf, const ushort_t* __restrict__ xbf,
    const ushort_t* __restrict__ wlt, float* __restrict__ xxx,
    float* __restrict__ ha)
{
  const int nt = blockIdx.y;
  const int bm = blockIdx.x * 32;
  const ushort_t* A = (nt < 3) ? zbf : xbf;
  const int wrow = nt * 32;
  const int lane = threadIdx.x;
  const int l15 = lane & 15, g = lane >> 4;
  f32x4 acc[2][2];
  #pragma unroll
  for (int i = 0; i < 2; i++)
    #pragma unroll
    for (int j = 0; j < 2; j++) acc[i][j] = (f32x4){0.f,0.f,0.f,0.f};
  bf16x8 a0[2], b0[2], a1[2], b1[2];
  #define LLA(dst, kk) { \
    dst[0] = *(const bf16x8*)&A[(size_t)(bm + l15)*C_DIM + (kk) + g*8]; \
    dst[1] = *(const bf16x8*)&A[(size_t)(bm + 16 + l15)*C_DIM + (kk) + g*8]; }
  #define LLB(dst, kk) { \
    dst[0] = *(const bf16x8*)&wlt[(size_t)(wrow + l15)*C_DIM + (kk) + g*8]; \
    dst[1] = *(const bf16x8*)&wlt[(size_t)(wrow + 16 + l15)*C_DIM + (kk) + g*8]; }
  LLA(a0, 0); LLB(b0, 0);
  for (int k0 = 0; k0 < C_DIM; k0 += 64) {
    LLA(a1, k0+32); LLB(b1, k0+32);
    #pragma unroll
    for (int i = 0; i < 2; i++)
      #pragma unroll
      for (int j = 0; j < 2; j++) acc[i][j] = MFMA16(a0[i], b0[j], acc[i][j]);
    if (k0 + 64 < C_DIM) { LLA(a0, k0+64); LLB(b0, k0+64); }
    #pragma unroll
    for (int i = 0; i < 2; i++)
      #pragma unroll
      for (int j = 0; j < 2; j++) acc[i][j] = MFMA16(a1[i], b1[j], acc[i][j]);
  }
  #undef LLA
  #undef LLB
  #pragma unroll
  for (int i = 0; i < 2; i++)
    #pragma unroll
    for (int j = 0; j < 2; j++)
      #pragma unroll
      for (int r = 0; r < 4; r++) {
        const int t = bm + i*16 + g*4 + r;
        const int col = wrow + j*16 + l15;
        const float val = tanhf(acc[i][j][r]);
        if (nt < 3) xxx[(size_t)t*96 + col] = val;
        else        ha[(size_t)t*128 + col - 96] = val;
      }
}

// ---------------- 4. mix ----------------
__global__ __launch_bounds__(256) void mix_kernel(
    const float* __restrict__ x, const float* __restrict__ dxp,
    const float* __restrict__ xxx,
    const float* __restrict__ maa_r, const float* __restrict__ maa_k,
    const float* __restrict__ maa_v, const float* __restrict__ w2,
    ushort_t* __restrict__ xq, ushort_t* __restrict__ xk,
    ushort_t* __restrict__ xv)
{
  __shared__ float xs[8][96];
  const int t0 = blockIdx.x * 8;
  const int tid = threadIdx.x;
  #pragma unroll
  for (int i = 0; i < 3; i++) {
    const int u = tid + i*256;
    if (u < 768) {
      const int r = u / 96, cc = u % 96;
      xs[r][cc] = xxx[(size_t)(t0+r)*96 + cc];
    }
  }
  __syncthreads();
  const int c = tid * 4;
  float4 xc[8], dx[8];
  #pragma unroll
  for (int r = 0; r < 8; r++) {
    xc[r] = *(const float4*)&x[(size_t)(t0+r)*C_DIM + c];
    dx[r] = *(const float4*)&dxp[(size_t)(t0+r)*C_DIM + c];
  }
  const float* maas[3] = {maa_r, maa_k, maa_v};
  ushort_t* outs[3] = {xq, xk, xv};
  #pragma unroll
  for (int n = 0; n < 3; n++) {
    const float4 mv = *(const float4*)&maas[n][c];
    float m[8][4];
    #pragma unroll
    for (int r = 0; r < 8; r++) {
      m[r][0] = mv.x; m[r][1] = mv.y; m[r][2] = mv.z; m[r][3] = mv.w;
    }
    #pragma unroll 8
    for (int d = 0; d < 32; d++) {
      const float4 w = *(const float4*)&w2[((size_t)n*32 + d)*C_DIM + c];
      #pragma unroll
      for (int r = 0; r < 8; r++) {
        const float xv2 = xs[r][n*32 + d];
        m[r][0] += xv2*w.x; m[r][1] += xv2*w.y;
        m[r][2] += xv2*w.z; m[r][3] += xv2*w.w;
      }
    }
    #pragma unroll
    for (int r = 0; r < 8; r++)
      pack4(&outs[n][(size_t)(t0+r)*C_DIM + c],
            xc[r].x + dx[r].x*m[r][0], xc[r].y + dx[r].y*m[r][1],
            xc[r].z + dx[r].z*m[r][2], xc[r].w + dx[r].w*m[r][3]);
  }
}

// ---------------- 5. hm ----------------
__global__ __launch_bounds__(256) void hm_kernel(
    const float* __restrict__ ha, const float* __restrict__ hw2,
    float* __restrict__ hm, int T)
{
  const int t = blockIdx.x*4 + (threadIdx.x >> 6);
  const int u = threadIdx.x & 63;
  const int n = u >> 4, h = u & 15;
  float s = 0.f;
  #pragma unroll 8
  for (int d = 0; d < 32; d++)
    s += ha[(size_t)t*128 + n*32 + d] * hw2[(size_t)(n*32 + d)*16 + h];
  hm[((size_t)n*T + t)*16 + h] = s * (1.f/16.f);
}

// ---------------- 6. weight prep ----------------
__global__ __launch_bounds__(256) void wprep_kernel(
    const float* __restrict__ w0, const float* __restrict__ w1,
    const float* __restrict__ w2, const float* __restrict__ w3,
    ushort_t* __restrict__ o0, ushort_t* __restrict__ o1,
    ushort_t* __restrict__ o2, ushort_t* __restrict__ o3)
{
  const float* W; ushort_t* O;
  if (blockIdx.z == 0)      { W = w0; O = o0; }
  else if (blockIdx.z == 1) { W = w1; O = o1; }
  else if (blockIdx.z == 2) { W = w2; O = o2; }
  else                      { W = w3; O = o3; }
  __shared__ float tile[32][33];
  const int k0 = blockIdx.x*32, n0 = blockIdx.y*32;
  const int r = threadIdx.x >> 3, c4 = (threadIdx.x & 7) * 4;
  const float4 v = *(const float4*)&W[(size_t)(k0+r)*C_DIM + n0 + c4];
  tile[r][c4+0] = v.x; tile[r][c4+1] = v.y;
  tile[r][c4+2] = v.z; tile[r][c4+3] = v.w;
  __syncthreads();
  pack4(&O[(size_t)(n0+r)*C_DIM + k0 + c4],
        tile[c4+0][r], tile[c4+1][r], tile[c4+2][r], tile[c4+3][r]);
}

// ---------------- 7. bf16 MFMA GEMM ----------------
__global__ __launch_bounds__(64)
__attribute__((amdgpu_waves_per_eu(2, 4)))
void gemm_bf16(
    const ushort_t* __restrict__ A, const ushort_t* __restrict__ Bt,
    float* __restrict__ Cm)
{
  const int bid = blockIdx.x;
  const int bn = (bid & 15) * 64;
  const int bm = (bid >> 4) * 32;
  const int lane = threadIdx.x;
  const int l15 = lane & 15, g = lane >> 4;
  f32x4 acc[2][4];
  #pragma unroll
  for (int i = 0; i < 2; i++)
    #pragma unroll
    for (int j = 0; j < 4; j++) acc[i][j] = (f32x4){0.f,0.f,0.f,0.f};
  bf16x8 a0[2], b0[4], a1[2], b1[4];
  #define LGA(dst, kk) { \
    _Pragma("unroll") \
    for (int i = 0; i < 2; i++) \
      dst[i] = *(const bf16x8*)&A[(size_t)(bm + i*16 + l15)*C_DIM + (kk) + g*8]; }
  #define LGB(dst, kk) { \
    _Pragma("unroll") \
    for (int j = 0; j < 4; j++) \
      dst[j] = *(const bf16x8*)&Bt[(size_t)(bn + j*16 + l15)*C_DIM + (kk) + g*8]; }
  LGA(a0, 0); LGB(b0, 0);
  for (int k0 = 0; k0 < C_DIM; k0 += 64) {
    LGA(a1, k0+32); LGB(b1, k0+32);
    #pragma unroll
    for (int i = 0; i < 2; i++)
      #pragma unroll
      for (int j = 0; j < 4; j++) acc[i][j] = MFMA16(a0[i], b0[j], acc[i][j]);
    if (k0 + 64 < C_DIM) { LGA(a0, k0+64); LGB(b0, k0+64); }
    #pragma unroll
    for (int i = 0; i < 2; i++)
      #pragma unroll
      for (int j = 0; j < 4; j++) acc[i][j] = MFMA16(a1[i], b1[j], acc[i][j]);
  }
  #undef LGA
  #undef LGB
  #pragma unroll
  for (int i = 0; i < 2; i++)
    #pragma unroll
    for (int j = 0; j < 4; j++)
      #pragma unroll
      for (int r = 0; r < 4; r++)
        Cm[(size_t)(bm + i*16 + g*4 + r)*C_DIM + bn + j*16 + l15] = acc[i][j][r];
}

// ---------------- 8. row LayerNorm -> bf16 ----------------
__global__ __launch_bounds__(256) void ln_rows(
    const float* __restrict__ in, ushort_t* __restrict__ outp,
    const float* __restrict__ g, const float* __restrict__ b, float scale)
{
  __shared__ float red[4];
  const int t = blockIdx.x;
  const int tid = threadIdx.x;
  const int c = tid*4;
  const float4 v = *(const float4*)&in[(size_t)t*C_DIM + c];
  float s = v.x+v.y+v.z+v.w;
  #pragma unroll
  for (int off = 32; off > 0; off >>= 1) s += __shfl_down(s, off, 64);
  if ((tid & 63) == 0) red[tid >> 6] = s;
  __syncthreads();
  const float mean = (red[0]+red[1]+red[2]+red[3]) * (1.0f/C_DIM);
  __syncthreads();
  const float d0 = v.x-mean, d1 = v.y-mean, d2 = v.z-mean, d3 = v.w-mean;
  float q = d0*d0 + d1*d1 + d2*d2 + d3*d3;
  #pragma unroll
  for (int off = 32; off > 0; off >>= 1) q += __shfl_down(q, off, 64);
  if ((tid & 63) == 0) red[tid >> 6] = q;
  __syncthreads();
  const float var = (red[0]+red[1]+red[2]+red[3]) * (1.0f/C_DIM);
  const float rstd = rsqrtf(var + 1e-5f);
  const float4 gv = *(const float4*)&g[c];
  const float4 bv = *(const float4*)&b[c];
  pack4(outp + (size_t)t*C_DIM + c,
        (d0*rstd*gv.x + bv.x)*scale, (d1*rstd*gv.y + bv.y)*scale,
        (d2*rstd*gv.z + bv.z)*scale, (d3*rstd*gv.w + bv.w)*scale);
}

// ---------------- 9. V transpose ----------------
__global__ __launch_bounds__(256) void vtrans_kernel(
    const ushort_t* __restrict__ vbf, ushort_t* __restrict__ Vt, int T)
{
  __shared__ ushort_t tile[32][36];
  const int t0 = blockIdx.x*32, c0 = blockIdx.y*32;
  const int r = threadIdx.x >> 3, c4 = (threadIdx.x & 7) * 4;
  const uint2 raw = *(const uint2*)&vbf[(size_t)(t0+r)*C_DIM + c0 + c4];
  tile[r][c4+0] = (ushort_t)(raw.x & 0xffffu);
  tile[r][c4+1] = (ushort_t)(raw.x >> 16);
  tile[r][c4+2] = (ushort_t)(raw.y & 0xffffu);
  tile[r][c4+3] = (ushort_t)(raw.y >> 16);
  __syncthreads();
  uint2 w;
  w.x = (unsigned)tile[c4+0][r] | ((unsigned)tile[c4+1][r] << 16);
  w.y = (unsigned)tile[c4+2][r] | ((unsigned)tile[c4+3][r] << 16);
  *(uint2*)&Vt[(size_t)(c0+r)*T + t0 + c4] = w;
}

// ---------------- 10. attention phase A: softmax stats (paired-pinned sc) --
__global__ __launch_bounds__(512)
__attribute__((amdgpu_waves_per_eu(2, 4)))
void attn_stats(
    const ushort_t* __restrict__ qbf, const ushort_t* __restrict__ kbf,
    const float* __restrict__ hmb, float* __restrict__ part_m,
    float* __restrict__ part_l, int T)
{
  __shared__ ushort_t ybuf[HEADS*TQ*PADS];
  __shared__ float ep[TQ*EPS];
  __shared__ float hpqf[TQ*16];
  __shared__ float hpkf[SCH*16];
  __shared__ float spk_l[SCH];

  const int tbi = (int)blockIdx.y;
  const int tb = (T/TQ) - 1 - tbi;                 // longest-first
  // paired-pinned: XCD i (== blockIdx.x under round-robin) serves chunks
  // {i, 7-i}: equal work per XCD AND 2MB K/V working set (L2-resident).
  const int sc = (tbi & 1) ? (7 - (int)blockIdx.x) : (int)blockIdx.x;
  const int t0 = tb * TQ;
  const int sbeg = sc * SCH;
  if (sbeg >= t0 + TQ) return;
  const int send = (sbeg + SCH < t0 + TQ) ? (sbeg + SCH) : (t0 + TQ);

  const int tid = threadIdx.x;
  const int w = tid >> 6, lane = tid & 63, l15 = lane & 15, g = lane >> 4;

  for (int i = tid; i < SCH*16; i += 512)
    hpkf[i] = hmb[((size_t)1*T + sbeg)*16 + i];
  if (tid < TQ*16)
    hpqf[tid] = hmb[((size_t)0*T + t0)*16 + tid];
  if (tid < SCH) {
    const float* src = hmb + ((size_t)1*T + sbeg + tid)*16;
    float s = 0.f;
    #pragma unroll
    for (int q4 = 0; q4 < 4; q4++) {
      const float4 v = *(const float4*)&src[q4*4];
      s += v.x + v.y + v.z + v.w;
    }
    spk_l[tid] = s;
  }

  const int hh[2] = {w, w + 8};
  bf16x8 qf[2][2];
  float slope[2];
  #pragma unroll
  for (int hd = 0; hd < 2; hd++) {
    #pragma unroll
    for (int kc = 0; kc < 2; kc++)
      qf[hd][kc] = *(const bf16x8*)
          &qbf[(size_t)(t0 + l15)*C_DIM + hh[hd]*64 + kc*32 + g*8];
    slope[hd] = exp2f(-0.5f * (float)(hh[hd] + 1));
  }
  float mrun[2] = {-1e30f, -1e30f}, lrun[2] = {0.f, 0.f};

  bf16x8 kf[2][2][2];
  #define LOADK(sbase) { \
    _Pragma("unroll") \
    for (int hd = 0; hd < 2; hd++) \
      _Pragma("unroll") \
      for (int sh = 0; sh < 2; sh++) \
        _Pragma("unroll") \
        for (int kc = 0; kc < 2; kc++) \
          kf[hd][sh][kc] = *(const bf16x8*)&kbf[ \
              (size_t)((sbase) + sh*16 + l15)*C_DIM + hh[hd]*64 + kc*32 + g*8]; }
  LOADK(sbeg);

  for (int s1 = sbeg; s1 < send; s1 += 32) {
    f32x4 acc[2][2];
    #pragma unroll
    for (int hd = 0; hd < 2; hd++)
      #pragma unroll
      for (int sh = 0; sh < 2; sh++) acc[hd][sh] = (f32x4){0.f,0.f,0.f,0.f};
    #pragma unroll
    for (int hd = 0; hd < 2; hd++) {
      #pragma unroll
      for (int sh = 0; sh < 2; sh++)
        #pragma unroll
        for (int kc = 0; kc < 2; kc++)
          acc[hd][sh] = MFMA16(kf[hd][sh][kc], qf[hd][kc], acc[hd][sh]);
      #pragma unroll
      for (int sh = 0; sh < 2; sh++)
        pack4(&ybuf[(size_t)(hh[hd]*TQ + l15)*PADS + sh*16 + g*4],
              acc[hd][sh][0], acc[hd][sh][1], acc[hd][sh][2], acc[hd][sh][3]);
    }
    {
      const int snx = (s1 + 32 < send) ? s1 + 32 : s1;
      LOADK(snx);
    }
    __syncthreads();
    EPHASE(hpqf, hpkf, spk_l);
    __syncthreads();
    float epv[2][4];
    #pragma unroll
    for (int sh = 0; sh < 2; sh++)
      *(float4*)epv[sh] = *(const float4*)&ep[l15*EPS + sh*16 + g*4];
    #pragma unroll
    for (int hd = 0; hd < 2; hd++) {
      const int t = t0 + l15;
      #pragma unroll
      for (int sh = 0; sh < 2; sh++)
        #pragma unroll
        for (int r = 0; r < 4; r++) {
          const int s = s1 + sh*16 + g*4 + r;
          if (s <= t) {
            const float y3 = acc[hd][sh][r] + epv[sh][r]
                - slope[hd]*(float)(t - s);
            const float d = y3 - mrun[hd];
            if (d > 0.f) { lrun[hd] = lrun[hd]*__expf(-d) + 1.f; mrun[hd] = y3; }
            else lrun[hd] += __expf(d);
          }
        }
    }
  }
  #undef LOADK
  #pragma unroll
  for (int hd = 0; hd < 2; hd++) {
    float M = mrun[hd], L = lrun[hd];
    #pragma unroll
    for (int mask = 16; mask < 64; mask <<= 1) {
      const float M2 = __shfl_xor(M, mask, 64);
      const float L2 = __shfl_xor(L, mask, 64);
      mlmerge(M, L, M2, L2);
    }
    if (g == 0) {
      part_m[(size_t)(sc*HEADS + hh[hd])*T + t0 + l15] = M;
      part_l[(size_t)(sc*HEADS + hh[hd])*T + t0 + l15] = L;
    }
  }
}

// ---------------- 11. merge partial (m,l) ----------------
__global__ __launch_bounds__(256) void ml_combine(
    const float* __restrict__ part_m, const float* __restrict__ part_l,
    float* __restrict__ m_fin, float* __restrict__ linv, int T)
{
  const int idx = blockIdx.x*256 + threadIdx.x;   // h*T + t
  const int t = idx & (T - 1);
  const int nsc = (t >> 8) + 1;
  float M = -1e30f, L = 0.f;
  for (int sc = 0; sc < nsc; sc++)
    mlmerge(M, L, part_m[(size_t)sc*HEADS*T + idx],
            part_l[(size_t)sc*HEADS*T + idx]);
  m_fin[idx] = M;
  linv[idx] = 1.f / L;
}

// ---------------- 12. attention phase B: apply (paired-pinned sc) ----------
__global__ __launch_bounds__(512)
__attribute__((amdgpu_waves_per_eu(2, 4)))
void attn_apply(
    const ushort_t* __restrict__ qbf, const ushort_t* __restrict__ kbf,
    const ushort_t* __restrict__ Vt, const float* __restrict__ hmb,
    const float* __restrict__ m_fin, const float* __restrict__ linv,
    float* __restrict__ P, int T)
{
  __shared__ ushort_t ybuf[HEADS*TQ*PADS];
  __shared__ float ep[TQ*EPS];
  __shared__ float hpqf[TQ*16], hoqf[TQ*16];
  __shared__ float hpkf[SCH*16], hokf[SCH*16];
  __shared__ float spk_l[SCH], spo_l[SCH];

  const int tbi = (int)blockIdx.y;
  const int tb = (T/TQ) - 1 - tbi;
  const int sc = (tbi & 1) ? (7 - (int)blockIdx.x) : (int)blockIdx.x;
  const int t0 = tb * TQ;
  const int sbeg = sc * SCH;
  if (sbeg >= t0 + TQ) return;
  const int send = (sbeg + SCH < t0 + TQ) ? (sbeg + SCH) : (t0 + TQ);
  const int prow0 = T*sc - 128*sc*(sc-1) - SCH*sc;

  const int tid = threadIdx.x;
  const int w = tid >> 6, lane = tid & 63, l15 = lane & 15, g = lane >> 4;

  for (int i = tid; i < SCH*16; i += 512) {
    hpkf[i] = hmb[((size_t)1*T + sbeg)*16 + i];
    hokf[i] = hmb[((size_t)3*T + sbeg)*16 + i];
  }
  if (tid < TQ*16) {
    hpqf[tid] = hmb[((size_t)0*T + t0)*16 + tid];
    hoqf[tid] = hmb[((size_t)2*T + t0)*16 + tid];
  }
  {
    const int s_l = tid & 255;
    const float* src = hmb + ((size_t)((tid < 256) ? 1 : 3)*T + sbeg + s_l)*16;
    float s = 0.f;
    #pragma unroll
    for (int q4 = 0; q4 < 4; q4++) {
      const float4 v = *(const float4*)&src[q4*4];
      s += v.x + v.y + v.z + v.w;
    }
    if (tid < 256) spk_l[s_l] = s; else spo_l[s_l] = s;
  }

  const int hh[2] = {w, w + 8};
  bf16x8 qf[2][2];
  float mt[2], li[2], slope[2];
  #pragma unroll
  for (int hd = 0; hd < 2; hd++) {
    #pragma unroll
    for (int kc = 0; kc < 2; kc++)
      qf[hd][kc] = *(const bf16x8*)
          &qbf[(size_t)(t0 + l15)*C_DIM + hh[hd]*64 + kc*32 + g*8];
    mt[hd] = m_fin[(size_t)hh[hd]*T + t0 + l15];
    li[hd] = linv[(size_t)hh[hd]*T + t0 + l15];
    slope[hd] = exp2f(-0.5f * (float)(hh[hd] + 1));
  }
  f32x4 oacc[2][4];
  #pragma unroll
  for (int hd = 0; hd < 2; hd++)
    #pragma unroll
    for (int vf = 0; vf < 4; vf++) oacc[hd][vf] = (f32x4){0.f,0.f,0.f,0.f};

  for (int s1 = sbeg; s1 < send; s1 += 32) {
    f32x4 acc[2][2];
    #pragma unroll
    for (int hd = 0; hd < 2; hd++)
      #pragma unroll
      for (int sh = 0; sh < 2; sh++) acc[hd][sh] = (f32x4){0.f,0.f,0.f,0.f};
    #pragma unroll
    for (int hd = 0; hd < 2; hd++) {
      #pragma unroll
      for (int sh = 0; sh < 2; sh++)
        #pragma unroll
        for (int kc = 0; kc < 2; kc++) {
          const bf16x8 kf = *(const bf16x8*)
              &kbf[(size_t)(s1 + sh*16 + l15)*C_DIM + hh[hd]*64 + kc*32 + g*8];
          acc[hd][sh] = MFMA16(kf, qf[hd][kc], acc[hd][sh]);
        }
      #pragma unroll
      for (int sh = 0; sh < 2; sh++)
        pack4(&ybuf[(size_t)(hh[hd]*TQ + l15)*PADS + sh*16 + g*4],
              acc[hd][sh][0], acc[hd][sh][1], acc[hd][sh][2], acc[hd][sh][3]);
    }
    __syncthreads();                     // bar1: y0 ready
    EPHASE(hpqf, hpkf, spk_l);
    __syncthreads();                     // bar2: ep ready; ybuf free
    {
      float epv[2][4];
      #pragma unroll
      for (int sh = 0; sh < 2; sh++)
        *(float4*)epv[sh] = *(const float4*)&ep[l15*EPS + sh*16 + g*4];
      #pragma unroll
      for (int hd = 0; hd < 2; hd++) {
        const int t = t0 + l15;
        #pragma unroll
        for (int sh = 0; sh < 2; sh++) {
          #pragma unroll
          for (int r = 0; r < 4; r++) {
            const int s = s1 + sh*16 + g*4 + r;
            float p = 0.f;
            if (s <= t) {
              const float y3 = acc[hd][sh][r] + epv[sh][r]
                  - slope[hd]*(float)(t - s);
              p = __expf(y3 - mt[hd]) * li[hd];
            }
            acc[hd][sh][r] = p;
          }
          pack4(&ybuf[(size_t)(hh[hd]*TQ + l15)*PADS + sh*16 + g*4],
                acc[hd][sh][0], acc[hd][sh][1], acc[hd][sh][2], acc[hd][sh][3]);
        }
      }
    }
    __syncthreads();                     // bar3: p ready
    EPHASE(hoqf, hokf, spo_l);
    __syncthreads();                     // bar4: ep2 ready; ybuf(p) free
    bf16x8 vv[2][4];
    #pragma unroll
    for (int hd = 0; hd < 2; hd++)
      #pragma unroll
      for (int vf = 0; vf < 4; vf++)
        vv[hd][vf] = *(const bf16x8*)
            &Vt[(size_t)(hh[hd]*64 + vf*16 + l15)*T + s1 + g*8];
    {
      float epv[2][4];
      #pragma unroll
      for (int sh = 0; sh < 2; sh++)
        *(float4*)epv[sh] = *(const float4*)&ep[l15*EPS + sh*16 + g*4];
      #pragma unroll
      for (int hd = 0; hd < 2; hd++)
        #pragma unroll
        for (int sh = 0; sh < 2; sh++)
          pack4(&ybuf[(size_t)(hh[hd]*TQ + l15)*PADS + sh*16 + g*4],
                acc[hd][sh][0] + epv[sh][0], acc[hd][sh][1] + epv[sh][1],
                acc[hd][sh][2] + epv[sh][2], acc[hd][sh][3] + epv[sh][3]);
    }
    #pragma unroll
    for (int hd = 0; hd < 2; hd++) {
      const bf16x8 pa = *(const bf16x8*)
          &ybuf[(size_t)(hh[hd]*TQ + l15)*PADS + g*8];
      #pragma unroll
      for (int vf = 0; vf < 4; vf++)
        oacc[hd][vf] = MFMA16(pa, vv[hd][vf], oacc[hd][vf]);
    }
  }
  #pragma unroll
  for (int hd = 0; hd < 2; hd++)
    #pragma unroll
    for (int vf = 0; vf < 4; vf++)
      #pragma unroll
      for (int r = 0; r < 4; r++)
        P[(size_t)(prow0 + t0 + g*4 + r)*C_DIM + hh[hd]*64 + vf*16 + l15]
            = oacc[hd][vf][r];
}

// ---------------- 13. reduce partials + LayerNorm -> bf16 ----------------
__global__ __launch_bounds__(256) void reduce_ln(
    const float* __restrict__ P, ushort_t* __restrict__ outp,
    const float* __restrict__ g, const float* __restrict__ b, int T)
{
  __shared__ float red[4];
  const int t = blockIdx.x;
  const int tid = threadIdx.x;
  const int c = tid*4;
  const int nsc = (t >> 8) + 1;
  float4 v = make_float4(0.f, 0.f, 0.f, 0.f);
  int off = 0;
  for (int sc = 0; sc < nsc; sc++) {
    const int row = off + t - sc*SCH;
    const float4 pv = *(const float4*)&P[(size_t)row*C_DIM + c];
    v.x += pv.x; v.y += pv.y; v.z += pv.z; v.w += pv.w;
    off += T - SCH*sc;
  }
  float s = v.x+v.y+v.z+v.w;
  #pragma unroll
  for (int o = 32; o > 0; o >>= 1) s += __shfl_down(s, o, 64);
  if ((tid & 63) == 0) red[tid >> 6] = s;
  __syncthreads();
  const float mean = (red[0]+red[1]+red[2]+red[3]) * (1.0f/C_DIM);
  __syncthreads();
  const float d0 = v.x-mean, d1 = v.y-mean, d2 = v.z-mean, d3 = v.w-mean;
  float q = d0*d0 + d1*d1 + d2*d2 + d3*d3;
  #pragma unroll
  for (int o = 32; o > 0; o >>= 1) q += __shfl_down(q, o, 64);
  if ((tid & 63) == 0) red[tid >> 6] = q;
  __syncthreads();
  const float var = (red[0]+red[1]+red[2]+red[3]) * (1.0f/C_DIM);
  const float rstd = rsqrtf(var + 1e-5f);
  const float4 gv = *(const float4*)&g[c];
  const float4 bv = *(const float4*)&b[c];
  pack4(outp + (size_t)t*C_DIM + c,
        d0*rstd*gv.x + bv.x, d1*rstd*gv.y + bv.y,
        d2*rstd*gv.z + bv.z, d3*rstd*gv.w + bv.w);
}

// ---------------- launcher ----------------
extern "C" void kernel_launch(void* const* d_in, const int* in_sizes, int n_in,
                              void* d_out, int out_size, void* d_ws, size_t ws_size,
                              hipStream_t stream)
{
  const float* x      = (const float*)d_in[0];
  const float* shift  = (const float*)d_in[1];
  const float* maa_x  = (const float*)d_in[2];
  const float* maa_r  = (const float*)d_in[3];
  const float* maa_k  = (const float*)d_in[4];
  const float* maa_v  = (const float*)d_in[5];
  const float* w1     = (const float*)d_in[6];
  const float* w2     = (const float*)d_in[7];
  const float* hw1    = (const float*)d_in[8];
  const float* hw2    = (const float*)d_in[9];
  const float* w_r    = (const float*)d_in[10];
  const float* w_k    = (const float*)d_in[11];
  const float* w_v    = (const float*)d_in[12];
  const float* w_o    = (const float*)d_in[13];
  const float* ln_r_g = (const float*)d_in[14];
  const float* ln_r_b = (const float*)d_in[15];
  const float* ln_k_g = (const float*)d_in[16];
  const float* ln_k_b = (const float*)d_in[17];
  const float* ln_v_g = (const float*)d_in[18];
  const float* ln_v_b = (const float*)d_in[19];
  const float* ln_x_g = (const float*)d_in[20];
  const float* ln_x_b = (const float*)d_in[21];

  const int T = in_sizes[0] / C_DIM;            // 2048
  const size_t MM = (size_t)T * C_DIM;          // 2M f32 elems
  const size_t HF = MM / 2;                     // bf16 tensor in f32 units

  float* ws = (float*)d_ws;
  float*    P      = ws;
  float*    dxprev = ws;                          // MM
  ushort_t* zbf    = (ushort_t*)(ws + MM);        // HF
  ushort_t* xbf    = (ushort_t*)(ws + MM + HF);   // HF
  float*    gtmp   = ws + 2*MM;                   // MM
  ushort_t* xqb    = (ushort_t*)(ws + 3*MM);      // HF
  ushort_t* xkb    = (ushort_t*)(ws + 3*MM + HF); // HF
  ushort_t* xvb    = (ushort_t*)(ws + 4*MM);      // HF
  float* base2 = ws + 4*MM + HF;                  // = 4.5*MM
  ushort_t* qbf = (ushort_t*)(base2 + 0*HF);
  ushort_t* kbf = (ushort_t*)(base2 + 1*HF);
  ushort_t* vbf = (ushort_t*)(base2 + 2*HF);
  ushort_t* Vt  = (ushort_t*)(base2 + 3*HF);
  ushort_t* wtr = (ushort_t*)(base2 + 4*HF);
  ushort_t* wtk = wtr + (size_t)C_DIM*C_DIM;
  ushort_t* wtv = wtk + (size_t)C_DIM*C_DIM;
  ushort_t* wto = wtv + (size_t)C_DIM*C_DIM;
  float* after_w = base2 + 4*HF + (size_t)2*C_DIM*C_DIM;
  ushort_t* wlt = (ushort_t*)after_w;
  float* xxx    = after_w + 131072;
  float* ha     = xxx + (size_t)T*96;
  float* hmb    = ha + (size_t)T*128;
  float* part_m = hmb + (size_t)4*T*16;
  float* part_l = part_m + (size_t)8*HEADS*T;
  float* m_fin  = part_l + (size_t)8*HEADS*T;
  float* linv   = m_fin + (size_t)HEADS*T;
  ushort_t* abf = (ushort_t*)(linv + (size_t)HEADS*T);

  prep_kernel<<<T, 256, 0, stream>>>(x, shift, maa_x, dxprev, zbf, xbf);
  wlora_prep<<<dim3(C_DIM/32, 7), 256, 0, stream>>>(w1, hw1, wlt);
  lora_gemm<<<dim3(T/32, 7), 64, 0, stream>>>(zbf, xbf, wlt, xxx, ha);
  mix_kernel<<<T/8, 256, 0, stream>>>(x, dxprev, xxx, maa_r, maa_k, maa_v, w2,
                                      xqb, xkb, xvb);
  hm_kernel<<<T/4, 256, 0, stream>>>(ha, hw2, hmb, T);
  wprep_kernel<<<dim3(32, 32, 4), 256, 0, stream>>>(
      w_r, w_k, w_v, w_o, wtr, wtk, wtv, wto);

  const int ggemm = (T/32) * (C_DIM/64);
  gemm_bf16<<<ggemm, 64, 0, stream>>>(xqb, wtr, gtmp);
  ln_rows<<<T, 256, 0, stream>>>(gtmp, qbf, ln_r_g, ln_r_b, 0.125f);
  gemm_bf16<<<ggemm, 64, 0, stream>>>(xkb, wtk, gtmp);
  ln_rows<<<T, 256, 0, stream>>>(gtmp, kbf, ln_k_g, ln_k_b, 1.0f);
  gemm_bf16<<<ggemm, 64, 0, stream>>>(xvb, wtv, gtmp);
  ln_rows<<<T, 256, 0, stream>>>(gtmp, vbf, ln_v_g, ln_v_b, 1.0f);
  vtrans_kernel<<<dim3(T/32, C_DIM/32), 256, 0, stream>>>(vbf, Vt, T);

  attn_stats<<<dim3(8, T/TQ), 512, 0, stream>>>(
      qbf, kbf, hmb, part_m, part_l, T);
  ml_combine<<<(HEADS*T)/256, 256, 0, stream>>>(part_m, part_l, m_fin, linv, T);
  attn_apply<<<dim3(8, T/TQ), 512, 0, stream>>>(
      qbf, kbf, Vt, hmb, m_fin, linv, P, T);

  reduce_ln<<<T, 256, 0, stream>>>(P, abf, ln_x_g, ln_x_b, T);
  gemm_bf16<<<ggemm, 64, 0, stream>>>(abf, wto, (float*)d_out);
}